// Round 1
// baseline (264.894 us; speedup 1.0000x reference)
//
#include <hip/hip_runtime.h>
#include <math.h>

// B=256, D=256, H=8, HD=32, FF=1024, M=2048
#define SCALE_F 0.17677669529663687f

// ---------------- generic NT GEMM: C[M,N] = alpha * A[M,K] @ B[N,K]^T (+bias, relu) ----
// batched over grid.z (zb) with strides, plus optional k-split (partials written at sCk)
__global__ __launch_bounds__(256) void gemm_nt(
    const float* __restrict__ A, int lda, long long sAz,
    const float* __restrict__ Bm, int ldb, long long sBz,
    float* __restrict__ C, int ldc, long long sCz, long long sCk,
    const float* __restrict__ bias,
    int M, int N, int K, float alpha, int relu, int kSplit)
{
    __shared__ float As[16][68];
    __shared__ float Bs[16][68];
    int z = blockIdx.z;
    int zb = z / kSplit, ks = z - zb * kSplit;
    A  += (long long)zb * sAz;
    Bm += (long long)zb * sBz;
    C  += (long long)zb * sCz + (long long)ks * sCk;
    int Klen = K / kSplit;
    int kbeg = ks * Klen, kend = kbeg + Klen;
    int tid = threadIdx.x;
    int tx = tid & 15, ty = tid >> 4;
    int r0 = blockIdx.y * 64, c0 = blockIdx.x * 64;
    float acc[4][4] = {};
    int lrow = tid >> 2, lc4 = (tid & 3) << 2;
    for (int k0 = kbeg; k0 < kend; k0 += 16) {
        float4 va = make_float4(0.f, 0.f, 0.f, 0.f);
        if (r0 + lrow < M) va = *(const float4*)(A + (long long)(r0 + lrow) * lda + k0 + lc4);
        As[lc4 + 0][lrow] = va.x; As[lc4 + 1][lrow] = va.y;
        As[lc4 + 2][lrow] = va.z; As[lc4 + 3][lrow] = va.w;
        float4 vb = make_float4(0.f, 0.f, 0.f, 0.f);
        if (c0 + lrow < N) vb = *(const float4*)(Bm + (long long)(c0 + lrow) * ldb + k0 + lc4);
        Bs[lc4 + 0][lrow] = vb.x; Bs[lc4 + 1][lrow] = vb.y;
        Bs[lc4 + 2][lrow] = vb.z; Bs[lc4 + 3][lrow] = vb.w;
        __syncthreads();
        #pragma unroll
        for (int k = 0; k < 16; ++k) {
            float4 a4 = *(const float4*)&As[k][ty << 2];
            float4 b4 = *(const float4*)&Bs[k][tx << 2];
            float a[4] = {a4.x, a4.y, a4.z, a4.w};
            float b[4] = {b4.x, b4.y, b4.z, b4.w};
            #pragma unroll
            for (int i = 0; i < 4; i++)
                #pragma unroll
                for (int j = 0; j < 4; j++)
                    acc[i][j] = fmaf(a[i], b[j], acc[i][j]);
        }
        __syncthreads();
    }
    #pragma unroll
    for (int i = 0; i < 4; i++) {
        int r = r0 + (ty << 2) + i;
        if (r >= M) continue;
        #pragma unroll
        for (int j = 0; j < 4; j++) {
            int c = c0 + (tx << 2) + j;
            if (c >= N) continue;
            float v = acc[i][j] * alpha;
            if (bias) v += bias[c];
            if (relu) v = fmaxf(v, 0.f);
            C[(long long)r * ldc + c] = v;
        }
    }
}

__global__ void reduce_parts(const float* __restrict__ parts, int np, long long stride,
                             const float* __restrict__ bias, int N, int relu,
                             float* __restrict__ out, int total)
{
    int i = blockIdx.x * 256 + threadIdx.x;
    if (i >= total) return;
    float s = 0.f;
    for (int p = 0; p < np; p++) s += parts[(long long)p * stride + i];
    if (bias) s += bias[i % N];
    if (relu) s = fmaxf(s, 0.f);
    out[i] = s;
}

// per-row L2 norms: rows 0..255 = src, rows 256..2303 = memory
__global__ void row_norms(const float* __restrict__ src, const float* __restrict__ mem,
                          float* __restrict__ nx, float* __restrict__ nm, float* __restrict__ nm2)
{
    int r = blockIdx.x;
    int lane = threadIdx.x;          // 64 lanes
    const float* row = (r < 256) ? (src + (long long)r * 256) : (mem + (long long)(r - 256) * 256);
    float4 v = *(const float4*)(row + lane * 4);
    float ss = v.x * v.x + v.y * v.y + v.z * v.z + v.w * v.w;
    for (int off = 32; off; off >>= 1) ss += __shfl_down(ss, off, 64);
    if (lane == 0) {
        if (r < 256) nx[r] = fmaxf(sqrtf(ss), 1e-8f);
        else { nm[r - 256] = fmaxf(sqrtf(ss), 1e-8f); nm2[r - 256] = ss; }
    }
}

// surprises[b] = total==0 ? 1 : 1 - max_m dot(b,m)/(nx[b]*nm[m])
__global__ __launch_bounds__(256) void surprise_k(const float* __restrict__ simdot,
        const float* __restrict__ nx, const float* __restrict__ nm, const float* __restrict__ nm2,
        float* __restrict__ sur)
{
    __shared__ float red[256];
    int b = blockIdx.x, t = threadIdx.x;
    float tot = 0.f;
    for (int m = t; m < 2048; m += 256) tot += nm2[m];
    red[t] = tot; __syncthreads();
    for (int s = 128; s; s >>= 1) { if (t < s) red[t] += red[t + s]; __syncthreads(); }
    float total = red[0];
    __syncthreads();
    float invx = 1.f / nx[b];
    float mx = -1e30f;
    for (int m = t; m < 2048; m += 256) {
        float s = simdot[(long long)b * 2048 + m] * invx / nm[m];
        mx = fmaxf(mx, s);
    }
    red[t] = mx; __syncthreads();
    for (int s = 128; s; s >>= 1) { if (t < s) red[t] = fmaxf(red[t], red[t + s]); __syncthreads(); }
    if (t == 0) sur[b] = (total == 0.f) ? 1.f : 1.f - red[0];
}

// softmax over M+1 per (h,b) row; probs written in place, self prob to p_self
__global__ __launch_bounds__(256) void softmax_k(float* __restrict__ P,
        const float* __restrict__ qkv, float* __restrict__ p_self)
{
    int r = blockIdx.x;              // h*256 + b
    int h = r >> 8, b = r & 255;
    int t = threadIdx.x;
    __shared__ float red[256];
    __shared__ float s_sl;
    if (t < 32) {
        float q = qkv[b * 768 + h * 32 + t];
        float k = qkv[b * 768 + 256 + h * 32 + t];
        red[t] = q * k;
    }
    __syncthreads();
    if (t == 0) { float s = 0.f; for (int i = 0; i < 32; i++) s += red[i]; s_sl = s * SCALE_F; }
    __syncthreads();
    float sl = s_sl;
    float* row = P + (long long)r * 2048;
    float mx = sl;
    for (int m = t; m < 2048; m += 256) mx = fmaxf(mx, row[m]);
    red[t] = mx; __syncthreads();
    for (int s = 128; s; s >>= 1) { if (t < s) red[t] = fmaxf(red[t], red[t + s]); __syncthreads(); }
    mx = red[0]; __syncthreads();
    float sum = 0.f;
    for (int m = t; m < 2048; m += 256) { float e = __expf(row[m] - mx); row[m] = e; sum += e; }
    red[t] = sum; __syncthreads();
    for (int s = 128; s; s >>= 1) { if (t < s) red[t] += red[t + s]; __syncthreads(); }
    float es = __expf(sl - mx);
    float inv = 1.f / (red[0] + es);
    for (int m = t; m < 2048; m += 256) row[m] *= inv;
    if (t == 0) p_self[r] = es * inv;
}

// ctx[b, h*32+d] = sum_m probs[h,b,m] * v_mem[m, h*32+d]  + p_self*v_src (fused)
// grid: (64 b-tiles of 4, 8 heads); 256 thr = 8 m-chunks x 32 d
__global__ __launch_bounds__(256) void ctx_k(const float* __restrict__ probs,
        const float* __restrict__ kv, const float* __restrict__ p_self,
        const float* __restrict__ qkv, float* __restrict__ ctx)
{
    int b0 = blockIdx.x * 4, h = blockIdx.y;
    int t = threadIdx.x;
    int d = t & 31, mc = t >> 5;
    __shared__ float ps[4][2048];
    __shared__ float red[8][128];
    for (int bi = 0; bi < 4; bi++)
        for (int m = t; m < 2048; m += 256)
            ps[bi][m] = probs[((long long)h * 256 + b0 + bi) * 2048 + m];
    __syncthreads();
    float acc[4] = {0.f, 0.f, 0.f, 0.f};
    const float* vbase = kv + 256 + h * 32 + d;
    for (int m = mc * 256; m < mc * 256 + 256; ++m) {
        float v = vbase[(long long)m * 512];
        acc[0] = fmaf(ps[0][m], v, acc[0]);
        acc[1] = fmaf(ps[1][m], v, acc[1]);
        acc[2] = fmaf(ps[2][m], v, acc[2]);
        acc[3] = fmaf(ps[3][m], v, acc[3]);
    }
    for (int bi = 0; bi < 4; bi++) red[mc][d * 4 + bi] = acc[bi];
    __syncthreads();
    if (t < 128) {
        int dd = t >> 2, bi = t & 3;
        float s = 0.f;
        for (int m2 = 0; m2 < 8; m2++) s += red[m2][dd * 4 + bi];
        int b = b0 + bi;
        s += p_self[h * 256 + b] * qkv[b * 768 + 512 + h * 32 + dd];
        ctx[b * 256 + h * 32 + dd] = s;
    }
}

// O = LN(X + R) * g + be   (rows of 256)
__global__ __launch_bounds__(256) void ln_k(const float* __restrict__ X, const float* __restrict__ R,
        const float* __restrict__ g, const float* __restrict__ be, float* __restrict__ O)
{
    int r = blockIdx.x, t = threadIdx.x;
    __shared__ float red[256];
    float x = X[r * 256 + t] + R[r * 256 + t];
    red[t] = x; __syncthreads();
    for (int s = 128; s; s >>= 1) { if (t < s) red[t] += red[t + s]; __syncthreads(); }
    float mean = red[0] * (1.f / 256.f); __syncthreads();
    float c = x - mean;
    red[t] = c * c; __syncthreads();
    for (int s = 128; s; s >>= 1) { if (t < s) red[t] += red[t + s]; __syncthreads(); }
    float var = red[0] * (1.f / 256.f);
    float rstd = 1.f / sqrtf(var + 1e-5f);
    O[r * 256 + t] = c * rstd * g[t] + be[t];
}

// sequential accept scan (faithful to lax.scan semantics); inv[m] = source row b or -1
__global__ __launch_bounds__(256) void accept_k(const float* __restrict__ sur,
        const int* __restrict__ ptr, int* __restrict__ inv)
{
    int t = threadIdx.x;
    __shared__ float s_s[256];
    s_s[t] = sur[t];
    for (int m = t; m < 2048; m += 256) inv[m] = -1;
    __syncthreads();
    if (t == 0) {
        long long p = ptr[0];
        for (int b = 0; b < 256; ++b) {
            bool cond = (s_s[b] > 0.5f) || (p < 2048);
            if (cond) { inv[(int)(p % 2048)] = b; p++; }
        }
    }
}

__global__ __launch_bounds__(256) void memupd_k(const float* __restrict__ memory,
        const float* __restrict__ momentum, const float* __restrict__ scores,
        const float* __restrict__ hbuf, const float* __restrict__ sur, const int* __restrict__ inv,
        float* __restrict__ mem_o, float* __restrict__ mom_o, float* __restrict__ sc_o)
{
    int m = blockIdx.x, t = threadIdx.x;
    int b = inv[m];
    long long o = (long long)m * 256 + t;
    float xm = memory[o], mo = momentum[o];
    if (b >= 0) {
        float diff = hbuf[b * 256 + t] - xm;
        float nmom = 0.9f * mo + 0.1f * diff;
        mem_o[o] = xm + 0.1f * nmom;
        mom_o[o] = nmom;
        if (t == 0) sc_o[m] = sur[b];
    } else {
        mem_o[o] = xm;
        mom_o[o] = mo;
        if (t == 0) sc_o[m] = scores[m];
    }
}

extern "C" void kernel_launch(void* const* d_in, const int* in_sizes, int n_in,
                              void* d_out, int out_size, void* d_ws, size_t ws_size,
                              hipStream_t stream)
{
    const float* src      = (const float*)d_in[0];
    const float* memory   = (const float*)d_in[1];
    const float* momentum = (const float*)d_in[2];
    const float* scores   = (const float*)d_in[3];
    const float* ipw      = (const float*)d_in[4];
    const float* ipb      = (const float*)d_in[5];
    const float* out_w    = (const float*)d_in[6];
    const float* out_b    = (const float*)d_in[7];
    const float* w1       = (const float*)d_in[8];
    const float* b1       = (const float*)d_in[9];
    const float* w2       = (const float*)d_in[10];
    const float* b2       = (const float*)d_in[11];
    const float* g1       = (const float*)d_in[12];
    const float* be1      = (const float*)d_in[13];
    const float* g2       = (const float*)d_in[14];
    const float* be2      = (const float*)d_in[15];
    const int*   ptr      = (const int*)d_in[16];

    float* o = (float*)d_out;
    float* out_main = o;
    float* mem_o = o + 65536;
    float* mom_o = mem_o + 524288;
    float* sc_o  = mom_o + 524288;

    float* ws = (float*)d_ws;
    float* qkv       = ws;
    float* kv        = qkv + 196608;
    float* simdot    = kv + 1048576;
    float* probs     = simdot + 524288;
    float* p_self    = probs + 4194304;
    float* nx        = p_self + 2048;
    float* nm        = nx + 256;
    float* nm2       = nm + 2048;
    float* sur       = nm2 + 2048;
    float* ctx       = sur + 256;
    float* attn_out  = ctx + 65536;
    float* hbuf      = attn_out + 65536;
    float* ff1       = hbuf + 65536;
    float* ff2       = ff1 + 262144;
    int*   inv       = (int*)(ff2 + 65536);
    float* qkv_part  = (float*)(inv + 2048);
    float* attn_part = qkv_part + 393216;
    float* ff1_part  = attn_part + 262144;
    float* ff2_part  = ff1_part + 524288;

    row_norms<<<2304, 64, 0, stream>>>(src, memory, nx, nm, nm2);

    // qkv_src [256,768] = src @ ipw^T + ipb  (k-split 2)
    gemm_nt<<<dim3(12, 4, 2), 256, 0, stream>>>(src, 256, 0, ipw, 256, 0,
        qkv_part, 768, 0, 196608, nullptr, 256, 768, 256, 1.f, 0, 2);
    reduce_parts<<<768, 256, 0, stream>>>(qkv_part, 2, 196608, ipb, 768, 0, qkv, 196608);

    // kv_mem [2048,512] = memory @ ipw[256:768]^T + ipb[256:768]
    gemm_nt<<<dim3(8, 32, 1), 256, 0, stream>>>(memory, 256, 0, ipw + 65536, 256, 0,
        kv, 512, 0, 0, ipb + 256, 2048, 512, 256, 1.f, 0, 1);

    // simdot [256,2048] = src @ memory^T
    gemm_nt<<<dim3(32, 4, 1), 256, 0, stream>>>(src, 256, 0, memory, 256, 0,
        simdot, 2048, 0, 0, nullptr, 256, 2048, 256, 1.f, 0, 1);
    surprise_k<<<256, 256, 0, stream>>>(simdot, nx, nm, nm2, sur);

    // logits [H][B][M], batched per head (A/B col offsets stride 32)
    gemm_nt<<<dim3(32, 4, 8), 256, 0, stream>>>(qkv, 768, 32, kv, 512, 32,
        probs, 2048, 524288, 0, nullptr, 256, 2048, 32, SCALE_F, 0, 1);
    softmax_k<<<2048, 256, 0, stream>>>(probs, qkv, p_self);
    ctx_k<<<dim3(64, 8, 1), 256, 0, stream>>>(probs, kv, p_self, qkv, ctx);

    // attn_out = ctx @ out_w^T + out_b  (k-split 4)
    gemm_nt<<<dim3(4, 4, 4), 256, 0, stream>>>(ctx, 256, 0, out_w, 256, 0,
        attn_part, 256, 0, 65536, nullptr, 256, 256, 256, 1.f, 0, 4);
    reduce_parts<<<256, 256, 0, stream>>>(attn_part, 4, 65536, out_b, 256, 0, attn_out, 65536);

    ln_k<<<256, 256, 0, stream>>>(attn_out, src, g1, be1, hbuf);

    accept_k<<<1, 256, 0, stream>>>(sur, ptr, inv);
    memupd_k<<<2048, 256, 0, stream>>>(memory, momentum, scores, hbuf, sur, inv, mem_o, mom_o, sc_o);

    // ff1 = relu(h @ w1^T + b1)  (k-split 2)
    gemm_nt<<<dim3(16, 4, 2), 256, 0, stream>>>(hbuf, 256, 0, w1, 256, 0,
        ff1_part, 1024, 0, 262144, nullptr, 256, 1024, 256, 1.f, 0, 2);
    reduce_parts<<<1024, 256, 0, stream>>>(ff1_part, 2, 262144, b1, 1024, 1, ff1, 262144);

    // ff2 = ff1 @ w2^T + b2  (k-split 4)
    gemm_nt<<<dim3(4, 4, 4), 256, 0, stream>>>(ff1, 1024, 0, w2, 1024, 0,
        ff2_part, 256, 0, 65536, nullptr, 256, 256, 1024, 1.f, 0, 4);
    reduce_parts<<<256, 256, 0, stream>>>(ff2_part, 4, 65536, b2, 256, 0, ff2, 65536);

    ln_k<<<256, 256, 0, stream>>>(ff2, hbuf, g2, be2, out_main);
}